// Round 9
// baseline (293.800 us; speedup 1.0000x reference)
//
#include <hip/hip_runtime.h>

// Self-attention (SAGAN-style), B=4, C=512, N=4096, O=64.
// Round 18b: wave-specialized merged attn block (resubmit of r18; the r18
//   bench run died on container acquisition -- no kernel signal).
//   r17 post-mortem: non-attn time pinned at ~100us across 7 rounds of
//   proj edits -> proj is small; harness dispatches dominate the rest.
//   attn is the remaining controllable cost (68us).
//   Structural waste found: the two chalf blocks of each (b,mi) computed
//   IDENTICAL S tiles and IDENTICAL exp/E tiles (chip-wide 2x S-MFMA and
//   2x the exp/pack/E-write VALU+TRANS load -- the dominant busy pipe at
//   36.8%) just to have Ebuf in each block's own LDS.
//   Change: ONE 1024-thread block per (b,mi); ctg = w (0..15).
//   Waves 0-7 = producers (S + exp + E-write + PV of ctg 0-7, exactly the
//   r17 code); waves 8-15 = consumers (PV only of ctg 8-15, same shared
//   Ebuf). Chip-wide S-MFMA, exp, and f-reads halve. Branches are
//   wave-uniform -> shared raw barrier is legal. Grid 256 = 1 block/CU.
//   Keeps: fragment-linear fp8 ha, S/PV software pipeline, raw lgkm-only
//   barrier, setprio, f direct from L2, exp2 folding (no fmin clamp --
//   cvt_pk_fp8 saturates), MX fp8 PV (unit scales), bf16 S.
// Fragment chunk convention (32-row tiles, 16-k chunks, bf16 2B):
//   chunk[tile][q][lane][i] = M[idx = tile*32 + (lane&31)][k = q*16 + (lane>>5)*8 + i]
// 64-wide MX frag convention: lane holds M[lane&31][k = (lane>>5)*32 + i], i=0..31
//   (k indexes the PERMUTED n order; both operands permuted consistently).

#define N_PIX 4096
#define C_IN  512

typedef __attribute__((ext_vector_type(8)))  short bf16x8;
typedef __attribute__((ext_vector_type(16))) float f32x16;
typedef __attribute__((ext_vector_type(8)))  int   i32x8;

__device__ __forceinline__ float fexp2(float x) {
    return __builtin_amdgcn_exp2f(x);   // v_exp_f32 (base-2)
}

__device__ inline unsigned int f2bf(float f) {
    union { float f; unsigned u; } x; x.f = f;
    unsigned r = x.u + 0x7FFFu + ((x.u >> 16) & 1u);
    return r >> 16;
}

__device__ __forceinline__ unsigned cvt_pk_bf16(float a, float b) {
#if __has_builtin(__builtin_amdgcn_cvt_pk_bf16_f32)
    auto r = __builtin_amdgcn_cvt_pk_bf16_f32(a, b);
    unsigned u; __builtin_memcpy(&u, &r, 4); return u;
#else
    return f2bf(a) | (f2bf(b) << 16);
#endif
}

// pack 4 floats -> 4 OCP e4m3 bytes (HW-saturating)
__device__ __forceinline__ unsigned pk_fp8x4(float a, float b, float c, float d) {
    int v = 0;
    v = __builtin_amdgcn_cvt_pk_fp8_f32(a, b, v, false);
    v = __builtin_amdgcn_cvt_pk_fp8_f32(c, d, v, true);
    return (unsigned)v;
}

#define RAW_BARRIER() do { \
    __builtin_amdgcn_sched_barrier(0); \
    asm volatile("s_waitcnt lgkmcnt(0)" ::: "memory"); \
    __builtin_amdgcn_s_barrier(); \
    __builtin_amdgcn_sched_barrier(0); \
} while (0)

// ---------------------------------------------------------------------------
// pack_w (coalesced): grid 20, block 256. Tile tt: 0-1 f_w, 2-3 g_w, 4-19 h_w.
// f_w pre-scaled by 1/ln2 so attn can use exp2 directly.
__global__ __launch_bounds__(256) void pack_w(
    const float* __restrict__ f_w, const float* __restrict__ g_w,
    const float* __restrict__ h_w, unsigned short* __restrict__ wall)
{
    __shared__ __align__(16) unsigned short Ls[32 * 520];
    const int t  = threadIdx.x;
    const int tt = blockIdx.x;
    const float* W; int rbase;
    if (tt < 2)      { W = f_w; rbase = tt * 32; }
    else if (tt < 4) { W = g_w; rbase = (tt - 2) * 32; }
    else             { W = h_w; rbase = (tt - 4) * 32; }
    const float fs = (tt < 2) ? 1.442695041f : 1.0f;

    #pragma unroll
    for (int k = 0; k < 16; ++k) {
        const int off = (t + k * 256) * 4;
        const int row = off >> 9, col = off & 511;
        float4 v = *(const float4*)&W[(size_t)(rbase + row) * C_IN + col];
        uint2 pk; pk.x = cvt_pk_bf16(v.x * fs, v.y * fs); pk.y = cvt_pk_bf16(v.z * fs, v.w * fs);
        *(uint2*)&Ls[row * 520 + col] = pk;
    }
    __syncthreads();
    #pragma unroll
    for (int j = 0; j < 8; ++j) {
        const int o = t + j * 256;
        const int q = o >> 6, lq = o & 63;
        const int row = lq & 31, c0 = q * 16 + (lq >> 5) * 8;
        uint4 pk = *(const uint4*)&Ls[row * 520 + c0];
        *(uint4*)&wall[(size_t)tt * 16384 + (size_t)o * 8] = pk;
    }
}

// ---------------------------------------------------------------------------
// proj_v17: 512 blocks (256 h-path 64n, 256 fg-path 64n), single raw
// lgkm-only barrier per iteration, register x-prefetch rides across.
__global__ __launch_bounds__(512, 4) void proj_kernel(
    const float* __restrict__ x,
    const unsigned short* __restrict__ wall,
    const float* __restrict__ f_b, const float* __restrict__ g_b,
    const float* __restrict__ h_b,
    unsigned short* __restrict__ fa, unsigned short* __restrict__ gbuf,
    unsigned char* __restrict__ ha)
{
    __shared__ __align__(16) unsigned short Xf[2][4096];   // 16 KB
    const int t    = threadIdx.x;
    const int w    = t >> 6;
    const int l    = t & 63;
    const int half = l >> 5;
    const int tx = t & 15;
    const int ty = t >> 4;
    const int c0 = ty * 2;
    const int qs = c0 >> 4;
    const int woff = (c0 & 7);
    const int hfs = (c0 >> 3) & 1;

    const int blk = blockIdx.x;

    if (blk < 256) {
        // ================= h-path: 16 c-tiles x 64 n =================
        const int b  = blk >> 6;
        const int nb = blk & 63;
        const int n0g = nb * 64;
        const int n0 = tx * 4;

        f32x16 acc[2][2];
        #pragma unroll
        for (int j = 0; j < 2; ++j)
            #pragma unroll
            for (int s = 0; s < 2; ++s)
                #pragma unroll
                for (int r = 0; r < 16; ++r) acc[j][s][r] = 0.f;

        const unsigned short* wp0 = wall + (size_t)(4 + w * 2) * 16384 + (size_t)l * 8;
        const unsigned short* wp1 = wp0 + 16384;
        bf16x8 wc0 = *(const bf16x8*)wp0;
        bf16x8 wc1 = *(const bf16x8*)wp1;

        float4 v0 = *(const float4*)&x[((size_t)(b * C_IN + c0)) * N_PIX + n0g + n0];
        float4 v1 = *(const float4*)&x[((size_t)(b * C_IN + c0 + 1)) * N_PIX + n0g + n0];

        for (int it = 0; it < 8; ++it) {
            {
                unsigned short* xb = &Xf[it & 1][0];
                const float a0[4] = {v0.x, v0.y, v0.z, v0.w};
                const float a1[4] = {v1.x, v1.y, v1.z, v1.w};
                #pragma unroll
                for (int j = 0; j < 4; ++j) {
                    const int n = n0 + j;
                    const int off = ((n >> 5) * 4 + qs) * 512
                                  + ((n & 31) + 32 * hfs) * 8 + woff;
                    *(unsigned*)&xb[off] = cvt_pk_bf16(a0[j], a1[j]);
                }
            }
            if (it < 7) {
                v0 = *(const float4*)&x[((size_t)(b * C_IN + (it + 1) * 64 + c0)) * N_PIX + n0g + n0];
                v1 = *(const float4*)&x[((size_t)(b * C_IN + (it + 1) * 64 + c0 + 1)) * N_PIX + n0g + n0];
            }
            RAW_BARRIER();   // publish ds_writes; x prefetch rides across
            const unsigned short* xb = &Xf[it & 1][0];
            #pragma unroll
            for (int q = 0; q < 4; ++q) {
                const int qn = (it * 4 + q + 1) & 31;
                bf16x8 wn0 = *(const bf16x8*)(wp0 + (size_t)qn * 512);
                bf16x8 wn1 = *(const bf16x8*)(wp1 + (size_t)qn * 512);
                bf16x8 x0 = *(const bf16x8*)&xb[(0 * 4 + q) * 512 + l * 8];
                bf16x8 x1 = *(const bf16x8*)&xb[(1 * 4 + q) * 512 + l * 8];
                acc[0][0] = __builtin_amdgcn_mfma_f32_32x32x16_bf16(x0, wc0, acc[0][0], 0, 0, 0);
                acc[0][1] = __builtin_amdgcn_mfma_f32_32x32x16_bf16(x1, wc0, acc[0][1], 0, 0, 0);
                acc[1][0] = __builtin_amdgcn_mfma_f32_32x32x16_bf16(x0, wc1, acc[1][0], 0, 0, 0);
                acc[1][1] = __builtin_amdgcn_mfma_f32_32x32x16_bf16(x1, wc1, acc[1][1], 0, 0, 0);
                wc0 = wn0; wc1 = wn1;
            }
            // no trailing barrier: read(it) and write(it+2) are separated
            // by barrier(it+1); write(it+1) targets the other buffer.
        }

        // epilogue: fragment-linear fp8 ha. nt = nb>>1, kt = nb&1.
        const int nt_ = nb >> 1, kt_ = nb & 1;
        #pragma unroll
        for (int j = 0; j < 2; ++j) {
            const int ctile = w * 2 + j;
            const int ch = ctile * 32 + (l & 31);
            const float hb = h_b[ch];
            unsigned char* hdst = ha
                + (((size_t)(b * 16 + ctile) * 32 + nt_) * 2 + kt_) * 2048
                + (size_t)(l & 31) * 32 + 16 * half;
            #pragma unroll
            for (int ns = 0; ns < 2; ++ns) {
                uint4 pk4;
                pk4.x = pk_fp8x4(acc[j][ns][0]  + hb, acc[j][ns][1]  + hb,
                                 acc[j][ns][2]  + hb, acc[j][ns][3]  + hb);
                pk4.y = pk_fp8x4(acc[j][ns][4]  + hb, acc[j][ns][5]  + hb,
                                 acc[j][ns][6]  + hb, acc[j][ns][7]  + hb);
                pk4.z = pk_fp8x4(acc[j][ns][8]  + hb, acc[j][ns][9]  + hb,
                                 acc[j][ns][10] + hb, acc[j][ns][11] + hb);
                pk4.w = pk_fp8x4(acc[j][ns][12] + hb, acc[j][ns][13] + hb,
                                 acc[j][ns][14] + hb, acc[j][ns][15] + hb);
                *(uint4*)&hdst[ns * 1024] = pk4;   // (row + 32*ns)*32
            }
        }
    } else {
        // ========== fg-path: 4 tiles x 64 n (256 blocks, 1 ntile/wave) =====
        const int blk2 = blk - 256;
        const int b   = blk2 >> 6;
        const int nb2 = blk2 & 63;
        const int n0g = nb2 * 64;
        const int n0 = tx * 4;
        const int tt    = w & 3;
        const int npair = w >> 2;

        f32x16 acc;
        #pragma unroll
        for (int r = 0; r < 16; ++r) acc[r] = 0.f;

        const unsigned short* wpf = wall + (size_t)tt * 16384 + (size_t)l * 8;
        bf16x8 wcf = *(const bf16x8*)wpf;

        float4 v0 = *(const float4*)&x[((size_t)(b * C_IN + c0)) * N_PIX + n0g + n0];
        float4 v1 = *(const float4*)&x[((size_t)(b * C_IN + c0 + 1)) * N_PIX + n0g + n0];

        for (int it = 0; it < 8; ++it) {
            {
                unsigned short* xb = &Xf[it & 1][0];
                const float a0[4] = {v0.x, v0.y, v0.z, v0.w};
                const float a1[4] = {v1.x, v1.y, v1.z, v1.w};
                #pragma unroll
                for (int j = 0; j < 4; ++j) {
                    const int n = n0 + j;
                    const int off = ((n >> 5) * 4 + qs) * 512
                                  + ((n & 31) + 32 * hfs) * 8 + woff;
                    *(unsigned*)&xb[off] = cvt_pk_bf16(a0[j], a1[j]);
                }
            }
            if (it < 7) {
                v0 = *(const float4*)&x[((size_t)(b * C_IN + (it + 1) * 64 + c0)) * N_PIX + n0g + n0];
                v1 = *(const float4*)&x[((size_t)(b * C_IN + (it + 1) * 64 + c0 + 1)) * N_PIX + n0g + n0];
            }
            RAW_BARRIER();
            const unsigned short* xb = &Xf[it & 1][0];
            #pragma unroll
            for (int q = 0; q < 4; ++q) {
                const int qn = (it * 4 + q + 1) & 31;
                bf16x8 wnf = *(const bf16x8*)(wpf + (size_t)qn * 512);
                bf16x8 x0 = *(const bf16x8*)&xb[(npair * 4 + q) * 512 + l * 8];
                acc = __builtin_amdgcn_mfma_f32_32x32x16_bf16(wcf, x0, acc, 0, 0, 0);
                wcf = wnf;
            }
        }

        unsigned short* buf = (tt < 2) ? fa : gbuf;
        const float* bias = (tt < 2) ? f_b : g_b;
        const float bscale = (tt < 2) ? 1.442695041f : 1.0f;
        const int ntile = nb2 * 2 + npair;
        #pragma unroll
        for (int j2 = 0; j2 < 4; ++j2) {
            const int o_base = (tt & 1) * 32 + 8 * j2 + 4 * half;
            float4 bv = *(const float4*)&bias[o_base];
            bv.x *= bscale; bv.y *= bscale; bv.z *= bscale; bv.w *= bscale;
            const int q  = o_base >> 4;
            const int lp = (l & 31) + 32 * (j2 & 1);
            uint2 pk;
            pk.x = cvt_pk_bf16(acc[4 * j2 + 0] + bv.x, acc[4 * j2 + 1] + bv.y);
            pk.y = cvt_pk_bf16(acc[4 * j2 + 2] + bv.z, acc[4 * j2 + 3] + bv.w);
            size_t off = (((size_t)(b * 128 + ntile) * 4 + q) * 64 + lp) * 8 + 4 * half;
            *(uint2*)&buf[off] = pk;
        }
    }
}

// ---------------------------------------------------------------------------
// attn_v18: merged wave-specialized block. 1024 threads, 16 waves;
// ctg = w. Waves 0-7: S + exp + E-write + PV; waves 8-15: PV only
// (shared Ebuf). grid 256 (= (b, mi)), 1 block/CU.
__global__ __launch_bounds__(1024, 4) void attn_kernel(
    const unsigned short* __restrict__ fa,
    const unsigned short* __restrict__ gbuf,
    const unsigned char* __restrict__ ha,
    const float* __restrict__ x,
    const float* __restrict__ gamma_p,
    float* __restrict__ out)
{
    __shared__ __align__(16) unsigned char Ebuf[2][64 * 136];  // 17.4 KB (fp8 E)
    __shared__ float den_part[4][64];
    __shared__ float den_inv[64];

    const int t    = threadIdx.x;
    const int w    = t >> 6;          // 0..15
    const int l    = t & 63;
    const int lane = l & 31;
    const int half = l >> 5;
    const bool prod = (w < 8);        // producer waves (wave-uniform)
    const int nsub = w & 3;           // producer S/E role (valid for w<8)
    const int mt   = w >> 2;          // (valid for w<8)

    const int blk = blockIdx.x;
    const int b   = blk & 3;
    const int mi  = blk >> 2;         // 0..63
    const int m0  = mi * 64;
    const int ctg = w;                // 0..15: PV channel group for ALL waves

    f32x16 acc[2];
    #pragma unroll
    for (int j = 0; j < 2; ++j)
        #pragma unroll
        for (int r = 0; r < 16; ++r) acc[j][r] = 0.f;

    float denp = 0.f;

    // fragment-linear h: per (nt,kt) a 2048B block; lane l owns bytes l*32..+32.
    const unsigned char* hptr = ha
        + (size_t)(b * 16 + ctg) * 131072 + (size_t)l * 32;
    i32x8 h0 = *(const i32x8*)hptr;
    i32x8 h1 = *(const i32x8*)(hptr + 2048);
    hptr += 4096;

    // producer-only state
    bf16x8 gfrag[4];
    bf16x8 ff[4];
    const unsigned short* fptr = fa + (size_t)b * (128 * 4) * 512
                               + (size_t)(nsub * 4) * 512 + (size_t)l * 8;

    if (prod) {
        const unsigned short* gp = gbuf
            + ((size_t)(b * 128 + mi * 2 + mt) * 4) * 512 + (size_t)l * 8;
        #pragma unroll
        for (int q = 0; q < 4; ++q)
            gfrag[q] = *(const bf16x8*)(gp + (size_t)q * 512);
        #pragma unroll
        for (int q = 0; q < 4; ++q)
            ff[q] = *(const bf16x8*)(fptr + (size_t)q * 512);
        fptr += 8192;

        // ---- prologue: S(0), exp(0), write slot0 ----
        f32x16 s;
        #pragma unroll
        for (int r = 0; r < 16; ++r) s[r] = 0.f;
        #pragma unroll
        for (int q = 0; q < 4; ++q)
            s = __builtin_amdgcn_mfma_f32_32x32x16_bf16(ff[q], gfrag[q], s, 0, 0, 0);
        // prefetch ff(1)
        #pragma unroll
        for (int q = 0; q < 4; ++q)
            ff[q] = *(const bf16x8*)(fptr + (size_t)q * 512);
        fptr += 8192;
        unsigned pkv[4];
        #pragma unroll
        for (int r4 = 0; r4 < 4; ++r4) {
            float e0 = fexp2(s[r4 * 4 + 0] - 8.656170f);
            float e1 = fexp2(s[r4 * 4 + 1] - 8.656170f);
            float e2 = fexp2(s[r4 * 4 + 2] - 8.656170f);
            float e3 = fexp2(s[r4 * 4 + 3] - 8.656170f);
            denp += (e0 + e1) + (e2 + e3);
            pkv[r4] = pk_fp8x4(e0, e1, e2, e3);
        }
        unsigned char* ew = &Ebuf[0][(mt * 32 + lane) * 136 + nsub * 32 + half * 16];
        *(unsigned long long*)(ew)     = (unsigned long long)pkv[0]
                                       | ((unsigned long long)pkv[1] << 32);
        *(unsigned long long*)(ew + 8) = (unsigned long long)pkv[2]
                                       | ((unsigned long long)pkv[3] << 32);
    }
    RAW_BARRIER();

    // ---- main loop: S/exp(nt+1) on producers; PV(nt) on all waves ----
    for (int nt = 0; nt < 31; ++nt) {
        f32x16 s;
        if (prod) {
            __builtin_amdgcn_s_setprio(1);
            #pragma unroll
            for (int r = 0; r < 16; ++r) s[r] = 0.f;
            #pragma unroll
            for (int q = 0; q < 4; ++q)
                s = __builtin_amdgcn_mfma_f32_32x32x16_bf16(ff[q], gfrag[q], s, 0, 0, 0);
            // prefetch ff(nt+2), in place
            #pragma unroll
            for (int q = 0; q < 4; ++q)
                ff[q] = *(const bf16x8*)(fptr + (size_t)q * 512);
            fptr += 8192;
            __builtin_amdgcn_s_setprio(0);
        }

        // PV(nt): E slot nt&1 (published), h(nt) in regs -- ALL waves
        {
            __builtin_amdgcn_s_setprio(1);
            const unsigned char* eb = &Ebuf[nt & 1][0];
            #pragma unroll
            for (int kt = 0; kt < 2; ++kt) {
                const unsigned char* e0p = eb + lane * 136 + kt * 64 + half * 32;
                union { i32x8 v; long d[4]; } b0, b1;
                #pragma unroll
                for (int j = 0; j < 4; ++j) {
                    b0.d[j] = *(const long*)(e0p + 8 * j);
                    b1.d[j] = *(const long*)(e0p + 32 * 136 + 8 * j);
                }
                const i32x8 av = kt ? h1 : h0;
                acc[0] = __builtin_amdgcn_mfma_scale_f32_32x32x64_f8f6f4(
                    av, b0.v, acc[0], 0, 0, 0, 127, 0, 127);
                acc[1] = __builtin_amdgcn_mfma_scale_f32_32x32x64_f8f6f4(
                    av, b1.v, acc[1], 0, 0, 0, 127, 0, 127);
            }
            __builtin_amdgcn_s_setprio(0);
            // prefetch h(nt+1), in place
            h0 = *(const i32x8*)hptr;
            h1 = *(const i32x8*)(hptr + 2048);
            hptr += 4096;
        }

        if (prod) {
            // exp(nt+1) + E-write to the opposite slot
            unsigned pkv[4];
            #pragma unroll
            for (int r4 = 0; r4 < 4; ++r4) {
                float e0 = fexp2(s[r4 * 4 + 0] - 8.656170f);
                float e1 = fexp2(s[r4 * 4 + 1] - 8.656170f);
                float e2 = fexp2(s[r4 * 4 + 2] - 8.656170f);
                float e3 = fexp2(s[r4 * 4 + 3] - 8.656170f);
                denp += (e0 + e1) + (e2 + e3);
                pkv[r4] = pk_fp8x4(e0, e1, e2, e3);
            }
            unsigned char* ew = &Ebuf[(nt + 1) & 1][(mt * 32 + lane) * 136 + nsub * 32 + half * 16];
            *(unsigned long long*)(ew)     = (unsigned long long)pkv[0]
                                           | ((unsigned long long)pkv[1] << 32);
            *(unsigned long long*)(ew + 8) = (unsigned long long)pkv[2]
                                           | ((unsigned long long)pkv[3] << 32);
        }

        // raw barrier: publish E(nt+1); vmcnt NOT drained.
        RAW_BARRIER();
    }

    // ---- epilogue: PV(31), all waves ----
    {
        const unsigned char* eb = &Ebuf[31 & 1][0];
        #pragma unroll
        for (int kt = 0; kt < 2; ++kt) {
            const unsigned char* e0p = eb + lane * 136 + kt * 64 + half * 32;
            union { i32x8 v; long d[4]; } b0, b1;
            #pragma unroll
            for (int j = 0; j < 4; ++j) {
                b0.d[j] = *(const long*)(e0p + 8 * j);
                b1.d[j] = *(const long*)(e0p + 32 * 136 + 8 * j);
            }
            const i32x8 av = kt ? h1 : h0;
            acc[0] = __builtin_amdgcn_mfma_scale_f32_32x32x64_f8f6f4(
                av, b0.v, acc[0], 0, 0, 0, 127, 0, 127);
            acc[1] = __builtin_amdgcn_mfma_scale_f32_32x32x64_f8f6f4(
                av, b1.v, acc[1], 0, 0, 0, 127, 0, 127);
        }
    }

    // ---- denominator (producers hold the partials) ----
    if (prod) {
        denp += __shfl_xor(denp, 32, 64);
        if (l < 32) den_part[nsub][mt * 32 + lane] = denp;
    }
    __syncthreads();
    if (t < 64) {
        float d = den_part[0][t] + den_part[1][t] + den_part[2][t] + den_part[3][t];
        den_inv[t] = 1.0f / d;
    }
    __syncthreads();

    const float gs = gamma_p[0];
    #pragma unroll
    for (int mt2 = 0; mt2 < 2; ++mt2) {
        const int mloc = mt2 * 32 + lane;
        const float dinv = den_inv[mloc];
        const int m = m0 + mloc;
        #pragma unroll
        for (int r = 0; r < 16; ++r) {
            const int c = ctg * 32 + (r & 3) + ((r >> 2) * 8) + half * 4;
            const size_t idx = ((size_t)(b * C_IN + c)) * N_PIX + m;
            out[idx] = gs * acc[mt2][r] * dinv + x[idx];
        }
    }
}

// ---------------------------------------------------------------------------
extern "C" void kernel_launch(void* const* d_in, const int* in_sizes, int n_in,
                              void* d_out, int out_size, void* d_ws, size_t ws_size,
                              hipStream_t stream)
{
    const float* x     = (const float*)d_in[0];
    const float* f_w   = (const float*)d_in[1];
    const float* f_b   = (const float*)d_in[2];
    const float* g_w   = (const float*)d_in[3];
    const float* g_b   = (const float*)d_in[4];
    const float* h_w   = (const float*)d_in[5];
    const float* h_b   = (const float*)d_in[6];
    const float* gamma = (const float*)d_in[7];
    float* out = (float*)d_out;

    unsigned short* fa   = (unsigned short*)d_ws;        // 1M shorts (2 MB)
    unsigned short* gbuf = fa + (1u << 20);              // 1M shorts (2 MB)
    unsigned char*  ha   = (unsigned char*)(gbuf + (1u << 20));  // 8 MB fp8 fragment-linear
    unsigned short* wall = (unsigned short*)(ha + (8u << 20));   // 640 KB

    pack_w<<<20, 256, 0, stream>>>(f_w, g_w, h_w, wall);

    proj_kernel<<<512, 512, 0, stream>>>(x, wall, f_b, g_b, h_b, fa, gbuf, ha);

    attn_kernel<<<256, 1024, 0, stream>>>(fa, gbuf, ha, x, gamma, out);
}

// Round 10
// 155.373 us; speedup vs baseline: 1.8909x; 1.8909x over previous
//
#include <hip/hip_runtime.h>

// Self-attention (SAGAN-style), B=4, C=512, N=4096, O=64.
// Round 19: fix the r18 register-spill catastrophe.
//   r18 post-mortem: WRITE_SIZE 34.8->526 MB, VGPR stuck at 64, pipes at
//   8% -> __launch_bounds__(1024,4)'s 2nd arg acted CUDA-style (blocks/CU)
//   and capped VGPR at 64; the merged producer needs ~110 -> ~50 regs/thread
//   spilled to scratch every iteration. The wave-specialized design never
//   actually ran in registers.
//   Changes:
//   - attn: __launch_bounds__(1024, 1) -> VGPR cap 128 (16-wave block fit).
//     Producer body reordered {S; ff-prefetch; exp->pkv; E-write} BEFORE the
//     PV cluster so s/pkv die early; peak liveness ~116 < 128.
//   - proj: (512,4) -> (512,2): same 64-cap suspicion (h-path acc alone is
//     64 VGPRs); cap 128 = exactly 2 blocks/CU at grid 512. If proj has
//     been spill-bound all session this is a large free win.
//   Everything else = r18: one 1024-thread block per (b,mi); ctg = w;
//   waves 0-7 producers (S+exp+E-write+PV), 8-15 consumers (PV only);
//   fragment-linear fp8 ha; raw lgkm-only barrier; setprio; f direct from
//   L2; exp2 folding (cvt_pk_fp8 saturates); MX fp8 PV; bf16 S. Grid 256.
// Fragment chunk convention (32-row tiles, 16-k chunks, bf16 2B):
//   chunk[tile][q][lane][i] = M[idx = tile*32 + (lane&31)][k = q*16 + (lane>>5)*8 + i]
// 64-wide MX frag convention: lane holds M[lane&31][k = (lane>>5)*32 + i], i=0..31
//   (k indexes the PERMUTED n order; both operands permuted consistently).

#define N_PIX 4096
#define C_IN  512

typedef __attribute__((ext_vector_type(8)))  short bf16x8;
typedef __attribute__((ext_vector_type(16))) float f32x16;
typedef __attribute__((ext_vector_type(8)))  int   i32x8;

__device__ __forceinline__ float fexp2(float x) {
    return __builtin_amdgcn_exp2f(x);   // v_exp_f32 (base-2)
}

__device__ inline unsigned int f2bf(float f) {
    union { float f; unsigned u; } x; x.f = f;
    unsigned r = x.u + 0x7FFFu + ((x.u >> 16) & 1u);
    return r >> 16;
}

__device__ __forceinline__ unsigned cvt_pk_bf16(float a, float b) {
#if __has_builtin(__builtin_amdgcn_cvt_pk_bf16_f32)
    auto r = __builtin_amdgcn_cvt_pk_bf16_f32(a, b);
    unsigned u; __builtin_memcpy(&u, &r, 4); return u;
#else
    return f2bf(a) | (f2bf(b) << 16);
#endif
}

// pack 4 floats -> 4 OCP e4m3 bytes (HW-saturating)
__device__ __forceinline__ unsigned pk_fp8x4(float a, float b, float c, float d) {
    int v = 0;
    v = __builtin_amdgcn_cvt_pk_fp8_f32(a, b, v, false);
    v = __builtin_amdgcn_cvt_pk_fp8_f32(c, d, v, true);
    return (unsigned)v;
}

#define RAW_BARRIER() do { \
    __builtin_amdgcn_sched_barrier(0); \
    asm volatile("s_waitcnt lgkmcnt(0)" ::: "memory"); \
    __builtin_amdgcn_s_barrier(); \
    __builtin_amdgcn_sched_barrier(0); \
} while (0)

// ---------------------------------------------------------------------------
// pack_w (coalesced): grid 20, block 256. Tile tt: 0-1 f_w, 2-3 g_w, 4-19 h_w.
// f_w pre-scaled by 1/ln2 so attn can use exp2 directly.
__global__ __launch_bounds__(256) void pack_w(
    const float* __restrict__ f_w, const float* __restrict__ g_w,
    const float* __restrict__ h_w, unsigned short* __restrict__ wall)
{
    __shared__ __align__(16) unsigned short Ls[32 * 520];
    const int t  = threadIdx.x;
    const int tt = blockIdx.x;
    const float* W; int rbase;
    if (tt < 2)      { W = f_w; rbase = tt * 32; }
    else if (tt < 4) { W = g_w; rbase = (tt - 2) * 32; }
    else             { W = h_w; rbase = (tt - 4) * 32; }
    const float fs = (tt < 2) ? 1.442695041f : 1.0f;

    #pragma unroll
    for (int k = 0; k < 16; ++k) {
        const int off = (t + k * 256) * 4;
        const int row = off >> 9, col = off & 511;
        float4 v = *(const float4*)&W[(size_t)(rbase + row) * C_IN + col];
        uint2 pk; pk.x = cvt_pk_bf16(v.x * fs, v.y * fs); pk.y = cvt_pk_bf16(v.z * fs, v.w * fs);
        *(uint2*)&Ls[row * 520 + col] = pk;
    }
    __syncthreads();
    #pragma unroll
    for (int j = 0; j < 8; ++j) {
        const int o = t + j * 256;
        const int q = o >> 6, lq = o & 63;
        const int row = lq & 31, c0 = q * 16 + (lq >> 5) * 8;
        uint4 pk = *(const uint4*)&Ls[row * 520 + c0];
        *(uint4*)&wall[(size_t)tt * 16384 + (size_t)o * 8] = pk;
    }
}

// ---------------------------------------------------------------------------
// proj_v19: r17 structure, launch_bounds (512,2) -> VGPR cap 128 (the
// (512,4) 64-cap likely forced h-path acc spills all session).
__global__ __launch_bounds__(512, 2) void proj_kernel(
    const float* __restrict__ x,
    const unsigned short* __restrict__ wall,
    const float* __restrict__ f_b, const float* __restrict__ g_b,
    const float* __restrict__ h_b,
    unsigned short* __restrict__ fa, unsigned short* __restrict__ gbuf,
    unsigned char* __restrict__ ha)
{
    __shared__ __align__(16) unsigned short Xf[2][4096];   // 16 KB
    const int t    = threadIdx.x;
    const int w    = t >> 6;
    const int l    = t & 63;
    const int half = l >> 5;
    const int tx = t & 15;
    const int ty = t >> 4;
    const int c0 = ty * 2;
    const int qs = c0 >> 4;
    const int woff = (c0 & 7);
    const int hfs = (c0 >> 3) & 1;

    const int blk = blockIdx.x;

    if (blk < 256) {
        // ================= h-path: 16 c-tiles x 64 n =================
        const int b  = blk >> 6;
        const int nb = blk & 63;
        const int n0g = nb * 64;
        const int n0 = tx * 4;

        f32x16 acc[2][2];
        #pragma unroll
        for (int j = 0; j < 2; ++j)
            #pragma unroll
            for (int s = 0; s < 2; ++s)
                #pragma unroll
                for (int r = 0; r < 16; ++r) acc[j][s][r] = 0.f;

        const unsigned short* wp0 = wall + (size_t)(4 + w * 2) * 16384 + (size_t)l * 8;
        const unsigned short* wp1 = wp0 + 16384;
        bf16x8 wc0 = *(const bf16x8*)wp0;
        bf16x8 wc1 = *(const bf16x8*)wp1;

        float4 v0 = *(const float4*)&x[((size_t)(b * C_IN + c0)) * N_PIX + n0g + n0];
        float4 v1 = *(const float4*)&x[((size_t)(b * C_IN + c0 + 1)) * N_PIX + n0g + n0];

        for (int it = 0; it < 8; ++it) {
            {
                unsigned short* xb = &Xf[it & 1][0];
                const float a0[4] = {v0.x, v0.y, v0.z, v0.w};
                const float a1[4] = {v1.x, v1.y, v1.z, v1.w};
                #pragma unroll
                for (int j = 0; j < 4; ++j) {
                    const int n = n0 + j;
                    const int off = ((n >> 5) * 4 + qs) * 512
                                  + ((n & 31) + 32 * hfs) * 8 + woff;
                    *(unsigned*)&xb[off] = cvt_pk_bf16(a0[j], a1[j]);
                }
            }
            if (it < 7) {
                v0 = *(const float4*)&x[((size_t)(b * C_IN + (it + 1) * 64 + c0)) * N_PIX + n0g + n0];
                v1 = *(const float4*)&x[((size_t)(b * C_IN + (it + 1) * 64 + c0 + 1)) * N_PIX + n0g + n0];
            }
            RAW_BARRIER();   // publish ds_writes; x prefetch rides across
            const unsigned short* xb = &Xf[it & 1][0];
            #pragma unroll
            for (int q = 0; q < 4; ++q) {
                const int qn = (it * 4 + q + 1) & 31;
                bf16x8 wn0 = *(const bf16x8*)(wp0 + (size_t)qn * 512);
                bf16x8 wn1 = *(const bf16x8*)(wp1 + (size_t)qn * 512);
                bf16x8 x0 = *(const bf16x8*)&xb[(0 * 4 + q) * 512 + l * 8];
                bf16x8 x1 = *(const bf16x8*)&xb[(1 * 4 + q) * 512 + l * 8];
                acc[0][0] = __builtin_amdgcn_mfma_f32_32x32x16_bf16(x0, wc0, acc[0][0], 0, 0, 0);
                acc[0][1] = __builtin_amdgcn_mfma_f32_32x32x16_bf16(x1, wc0, acc[0][1], 0, 0, 0);
                acc[1][0] = __builtin_amdgcn_mfma_f32_32x32x16_bf16(x0, wc1, acc[1][0], 0, 0, 0);
                acc[1][1] = __builtin_amdgcn_mfma_f32_32x32x16_bf16(x1, wc1, acc[1][1], 0, 0, 0);
                wc0 = wn0; wc1 = wn1;
            }
            // no trailing barrier: read(it) and write(it+2) are separated
            // by barrier(it+1); write(it+1) targets the other buffer.
        }

        // epilogue: fragment-linear fp8 ha. nt = nb>>1, kt = nb&1.
        const int nt_ = nb >> 1, kt_ = nb & 1;
        #pragma unroll
        for (int j = 0; j < 2; ++j) {
            const int ctile = w * 2 + j;
            const int ch = ctile * 32 + (l & 31);
            const float hb = h_b[ch];
            unsigned char* hdst = ha
                + (((size_t)(b * 16 + ctile) * 32 + nt_) * 2 + kt_) * 2048
                + (size_t)(l & 31) * 32 + 16 * half;
            #pragma unroll
            for (int ns = 0; ns < 2; ++ns) {
                uint4 pk4;
                pk4.x = pk_fp8x4(acc[j][ns][0]  + hb, acc[j][ns][1]  + hb,
                                 acc[j][ns][2]  + hb, acc[j][ns][3]  + hb);
                pk4.y = pk_fp8x4(acc[j][ns][4]  + hb, acc[j][ns][5]  + hb,
                                 acc[j][ns][6]  + hb, acc[j][ns][7]  + hb);
                pk4.z = pk_fp8x4(acc[j][ns][8]  + hb, acc[j][ns][9]  + hb,
                                 acc[j][ns][10] + hb, acc[j][ns][11] + hb);
                pk4.w = pk_fp8x4(acc[j][ns][12] + hb, acc[j][ns][13] + hb,
                                 acc[j][ns][14] + hb, acc[j][ns][15] + hb);
                *(uint4*)&hdst[ns * 1024] = pk4;   // (row + 32*ns)*32
            }
        }
    } else {
        // ========== fg-path: 4 tiles x 64 n (256 blocks, 1 ntile/wave) =====
        const int blk2 = blk - 256;
        const int b   = blk2 >> 6;
        const int nb2 = blk2 & 63;
        const int n0g = nb2 * 64;
        const int n0 = tx * 4;
        const int tt    = w & 3;
        const int npair = w >> 2;

        f32x16 acc;
        #pragma unroll
        for (int r = 0; r < 16; ++r) acc[r] = 0.f;

        const unsigned short* wpf = wall + (size_t)tt * 16384 + (size_t)l * 8;
        bf16x8 wcf = *(const bf16x8*)wpf;

        float4 v0 = *(const float4*)&x[((size_t)(b * C_IN + c0)) * N_PIX + n0g + n0];
        float4 v1 = *(const float4*)&x[((size_t)(b * C_IN + c0 + 1)) * N_PIX + n0g + n0];

        for (int it = 0; it < 8; ++it) {
            {
                unsigned short* xb = &Xf[it & 1][0];
                const float a0[4] = {v0.x, v0.y, v0.z, v0.w};
                const float a1[4] = {v1.x, v1.y, v1.z, v1.w};
                #pragma unroll
                for (int j = 0; j < 4; ++j) {
                    const int n = n0 + j;
                    const int off = ((n >> 5) * 4 + qs) * 512
                                  + ((n & 31) + 32 * hfs) * 8 + woff;
                    *(unsigned*)&xb[off] = cvt_pk_bf16(a0[j], a1[j]);
                }
            }
            if (it < 7) {
                v0 = *(const float4*)&x[((size_t)(b * C_IN + (it + 1) * 64 + c0)) * N_PIX + n0g + n0];
                v1 = *(const float4*)&x[((size_t)(b * C_IN + (it + 1) * 64 + c0 + 1)) * N_PIX + n0g + n0];
            }
            RAW_BARRIER();
            const unsigned short* xb = &Xf[it & 1][0];
            #pragma unroll
            for (int q = 0; q < 4; ++q) {
                const int qn = (it * 4 + q + 1) & 31;
                bf16x8 wnf = *(const bf16x8*)(wpf + (size_t)qn * 512);
                bf16x8 x0 = *(const bf16x8*)&xb[(npair * 4 + q) * 512 + l * 8];
                acc = __builtin_amdgcn_mfma_f32_32x32x16_bf16(wcf, x0, acc, 0, 0, 0);
                wcf = wnf;
            }
        }

        unsigned short* buf = (tt < 2) ? fa : gbuf;
        const float* bias = (tt < 2) ? f_b : g_b;
        const float bscale = (tt < 2) ? 1.442695041f : 1.0f;
        const int ntile = nb2 * 2 + npair;
        #pragma unroll
        for (int j2 = 0; j2 < 4; ++j2) {
            const int o_base = (tt & 1) * 32 + 8 * j2 + 4 * half;
            float4 bv = *(const float4*)&bias[o_base];
            bv.x *= bscale; bv.y *= bscale; bv.z *= bscale; bv.w *= bscale;
            const int q  = o_base >> 4;
            const int lp = (l & 31) + 32 * (j2 & 1);
            uint2 pk;
            pk.x = cvt_pk_bf16(acc[4 * j2 + 0] + bv.x, acc[4 * j2 + 1] + bv.y);
            pk.y = cvt_pk_bf16(acc[4 * j2 + 2] + bv.z, acc[4 * j2 + 3] + bv.w);
            size_t off = (((size_t)(b * 128 + ntile) * 4 + q) * 64 + lp) * 8 + 4 * half;
            *(uint2*)&buf[off] = pk;
        }
    }
}

// ---------------------------------------------------------------------------
// attn_v19: merged wave-specialized block, VGPR cap 128 via (1024,1).
// Producer body = {S; ff-prefetch; exp->pkv; E-write} BEFORE PV so s/pkv
// die early. Waves 0-7 producers, 8-15 PV-only. grid 256, 1 block/CU.
__global__ __launch_bounds__(1024, 1) void attn_kernel(
    const unsigned short* __restrict__ fa,
    const unsigned short* __restrict__ gbuf,
    const unsigned char* __restrict__ ha,
    const float* __restrict__ x,
    const float* __restrict__ gamma_p,
    float* __restrict__ out)
{
    __shared__ __align__(16) unsigned char Ebuf[2][64 * 136];  // 17.4 KB (fp8 E)
    __shared__ float den_part[4][64];
    __shared__ float den_inv[64];

    const int t    = threadIdx.x;
    const int w    = t >> 6;          // 0..15
    const int l    = t & 63;
    const int lane = l & 31;
    const int half = l >> 5;
    const bool prod = (w < 8);        // producer waves (wave-uniform)
    const int nsub = w & 3;           // producer S/E role (valid for w<8)
    const int mt   = w >> 2;          // (valid for w<8)

    const int blk = blockIdx.x;
    const int b   = blk & 3;
    const int mi  = blk >> 2;         // 0..63
    const int m0  = mi * 64;
    const int ctg = w;                // 0..15: PV channel group for ALL waves

    f32x16 acc[2];
    #pragma unroll
    for (int j = 0; j < 2; ++j)
        #pragma unroll
        for (int r = 0; r < 16; ++r) acc[j][r] = 0.f;

    float denp = 0.f;

    // fragment-linear h: per (nt,kt) a 2048B block; lane l owns bytes l*32..+32.
    const unsigned char* hptr = ha
        + (size_t)(b * 16 + ctg) * 131072 + (size_t)l * 32;
    i32x8 h0 = *(const i32x8*)hptr;
    i32x8 h1 = *(const i32x8*)(hptr + 2048);
    hptr += 4096;

    // producer-only state
    bf16x8 gfrag[4];
    bf16x8 ff[4];
    const unsigned short* fptr = fa + (size_t)b * (128 * 4) * 512
                               + (size_t)(nsub * 4) * 512 + (size_t)l * 8;

    if (prod) {
        const unsigned short* gp = gbuf
            + ((size_t)(b * 128 + mi * 2 + mt) * 4) * 512 + (size_t)l * 8;
        #pragma unroll
        for (int q = 0; q < 4; ++q)
            gfrag[q] = *(const bf16x8*)(gp + (size_t)q * 512);
        #pragma unroll
        for (int q = 0; q < 4; ++q)
            ff[q] = *(const bf16x8*)(fptr + (size_t)q * 512);
        fptr += 8192;

        // ---- prologue: S(0), exp(0), write slot0 ----
        f32x16 s;
        #pragma unroll
        for (int r = 0; r < 16; ++r) s[r] = 0.f;
        #pragma unroll
        for (int q = 0; q < 4; ++q)
            s = __builtin_amdgcn_mfma_f32_32x32x16_bf16(ff[q], gfrag[q], s, 0, 0, 0);
        // prefetch ff(1)
        #pragma unroll
        for (int q = 0; q < 4; ++q)
            ff[q] = *(const bf16x8*)(fptr + (size_t)q * 512);
        fptr += 8192;
        unsigned pkv[4];
        #pragma unroll
        for (int r4 = 0; r4 < 4; ++r4) {
            float e0 = fexp2(s[r4 * 4 + 0] - 8.656170f);
            float e1 = fexp2(s[r4 * 4 + 1] - 8.656170f);
            float e2 = fexp2(s[r4 * 4 + 2] - 8.656170f);
            float e3 = fexp2(s[r4 * 4 + 3] - 8.656170f);
            denp += (e0 + e1) + (e2 + e3);
            pkv[r4] = pk_fp8x4(e0, e1, e2, e3);
        }
        unsigned char* ew = &Ebuf[0][(mt * 32 + lane) * 136 + nsub * 32 + half * 16];
        *(unsigned long long*)(ew)     = (unsigned long long)pkv[0]
                                       | ((unsigned long long)pkv[1] << 32);
        *(unsigned long long*)(ew + 8) = (unsigned long long)pkv[2]
                                       | ((unsigned long long)pkv[3] << 32);
    }
    RAW_BARRIER();

    // ---- main loop ----
    for (int nt = 0; nt < 31; ++nt) {
        if (prod) {
            // S(nt+1) + exp(nt+1) + E-write, all before PV: s/pkv die here.
            __builtin_amdgcn_s_setprio(1);
            f32x16 s;
            #pragma unroll
            for (int r = 0; r < 16; ++r) s[r] = 0.f;
            #pragma unroll
            for (int q = 0; q < 4; ++q)
                s = __builtin_amdgcn_mfma_f32_32x32x16_bf16(ff[q], gfrag[q], s, 0, 0, 0);
            // prefetch ff(nt+2), in place
            #pragma unroll
            for (int q = 0; q < 4; ++q)
                ff[q] = *(const bf16x8*)(fptr + (size_t)q * 512);
            fptr += 8192;
            __builtin_amdgcn_s_setprio(0);
            unsigned pkv[4];
            #pragma unroll
            for (int r4 = 0; r4 < 4; ++r4) {
                float e0 = fexp2(s[r4 * 4 + 0] - 8.656170f);
                float e1 = fexp2(s[r4 * 4 + 1] - 8.656170f);
                float e2 = fexp2(s[r4 * 4 + 2] - 8.656170f);
                float e3 = fexp2(s[r4 * 4 + 3] - 8.656170f);
                denp += (e0 + e1) + (e2 + e3);
                pkv[r4] = pk_fp8x4(e0, e1, e2, e3);
            }
            // E-write to slot (nt+1)&1 (PV below reads slot nt&1 -- disjoint)
            unsigned char* ew = &Ebuf[(nt + 1) & 1][(mt * 32 + lane) * 136 + nsub * 32 + half * 16];
            *(unsigned long long*)(ew)     = (unsigned long long)pkv[0]
                                           | ((unsigned long long)pkv[1] << 32);
            *(unsigned long long*)(ew + 8) = (unsigned long long)pkv[2]
                                           | ((unsigned long long)pkv[3] << 32);
        }

        // PV(nt): E slot nt&1 (published), h(nt) in regs -- ALL waves
        {
            __builtin_amdgcn_s_setprio(1);
            const unsigned char* eb = &Ebuf[nt & 1][0];
            #pragma unroll
            for (int kt = 0; kt < 2; ++kt) {
                const unsigned char* e0p = eb + lane * 136 + kt * 64 + half * 32;
                union { i32x8 v; long d[4]; } b0, b1;
                #pragma unroll
                for (int j = 0; j < 4; ++j) {
                    b0.d[j] = *(const long*)(e0p + 8 * j);
                    b1.d[j] = *(const long*)(e0p + 32 * 136 + 8 * j);
                }
                const i32x8 av = kt ? h1 : h0;
                acc[0] = __builtin_amdgcn_mfma_scale_f32_32x32x64_f8f6f4(
                    av, b0.v, acc[0], 0, 0, 0, 127, 0, 127);
                acc[1] = __builtin_amdgcn_mfma_scale_f32_32x32x64_f8f6f4(
                    av, b1.v, acc[1], 0, 0, 0, 127, 0, 127);
            }
            __builtin_amdgcn_s_setprio(0);
            // prefetch h(nt+1), in place
            h0 = *(const i32x8*)hptr;
            h1 = *(const i32x8*)(hptr + 2048);
            hptr += 4096;
        }

        // raw barrier: publish E(nt+1); vmcnt NOT drained.
        RAW_BARRIER();
    }

    // ---- epilogue: PV(31), all waves ----
    {
        const unsigned char* eb = &Ebuf[31 & 1][0];
        #pragma unroll
        for (int kt = 0; kt < 2; ++kt) {
            const unsigned char* e0p = eb + lane * 136 + kt * 64 + half * 32;
            union { i32x8 v; long d[4]; } b0, b1;
            #pragma unroll
            for (int j = 0; j < 4; ++j) {
                b0.d[j] = *(const long*)(e0p + 8 * j);
                b1.d[j] = *(const long*)(e0p + 32 * 136 + 8 * j);
            }
            const i32x8 av = kt ? h1 : h0;
            acc[0] = __builtin_amdgcn_mfma_scale_f32_32x32x64_f8f6f4(
                av, b0.v, acc[0], 0, 0, 0, 127, 0, 127);
            acc[1] = __builtin_amdgcn_mfma_scale_f32_32x32x64_f8f6f4(
                av, b1.v, acc[1], 0, 0, 0, 127, 0, 127);
        }
    }

    // ---- denominator (producers hold the partials) ----
    if (prod) {
        denp += __shfl_xor(denp, 32, 64);
        if (l < 32) den_part[nsub][mt * 32 + lane] = denp;
    }
    __syncthreads();
    if (t < 64) {
        float d = den_part[0][t] + den_part[1][t] + den_part[2][t] + den_part[3][t];
        den_inv[t] = 1.0f / d;
    }
    __syncthreads();

    const float gs = gamma_p[0];
    #pragma unroll
    for (int mt2 = 0; mt2 < 2; ++mt2) {
        const int mloc = mt2 * 32 + lane;
        const float dinv = den_inv[mloc];
        const int m = m0 + mloc;
        #pragma unroll
        for (int r = 0; r < 16; ++r) {
            const int c = ctg * 32 + (r & 3) + ((r >> 2) * 8) + half * 4;
            const size_t idx = ((size_t)(b * C_IN + c)) * N_PIX + m;
            out[idx] = gs * acc[mt2][r] * dinv + x[idx];
        }
    }
}

// ---------------------------------------------------------------------------
extern "C" void kernel_launch(void* const* d_in, const int* in_sizes, int n_in,
                              void* d_out, int out_size, void* d_ws, size_t ws_size,
                              hipStream_t stream)
{
    const float* x     = (const float*)d_in[0];
    const float* f_w   = (const float*)d_in[1];
    const float* f_b   = (const float*)d_in[2];
    const float* g_w   = (const float*)d_in[3];
    const float* g_b   = (const float*)d_in[4];
    const float* h_w   = (const float*)d_in[5];
    const float* h_b   = (const float*)d_in[6];
    const float* gamma = (const float*)d_in[7];
    float* out = (float*)d_out;

    unsigned short* fa   = (unsigned short*)d_ws;        // 1M shorts (2 MB)
    unsigned short* gbuf = fa + (1u << 20);              // 1M shorts (2 MB)
    unsigned char*  ha   = (unsigned char*)(gbuf + (1u << 20));  // 8 MB fp8 fragment-linear
    unsigned short* wall = (unsigned short*)(ha + (8u << 20));   // 640 KB

    pack_w<<<20, 256, 0, stream>>>(f_w, g_w, h_w, wall);

    proj_kernel<<<512, 512, 0, stream>>>(x, wall, f_b, g_b, h_b, fa, gbuf, ha);

    attn_kernel<<<256, 1024, 0, stream>>>(fa, gbuf, ha, x, gamma, out);
}

// Round 11
// 152.392 us; speedup vs baseline: 1.9279x; 1.0196x over previous
//
#include <hip/hip_runtime.h>

// Self-attention (SAGAN-style), B=4, C=512, N=4096, O=64.
// Round 20: balanced producer/consumer roles in attn.
//   r19 post-mortem: spill fixed (WRITE 526->32.8MB), attn 68.7->52.9us.
//   Remaining stall: ~2700cy/iter of barrier wait -- producer waves ran
//   {S+exp+E-write+PV} while consumers ran only {PV} and parked at the
//   barrier. Iteration time = slowest (producer) chain.
//   Change: producers (w0-7) DROP their PV (chain = S+exp+E-write only);
//   consumers (w8-15) take 2 ctg of PV each (8 MX/nt; E B-frags shared
//   between the 2 ctg so LDS reads unchanged). The VALU/TRANS chain and
//   the MFMA chain now run CONCURRENTLY on each SIMD (2 prod + 2 cons).
//   Regs: producer ~80, consumer ~114 (acc 64 + h 32) -- both < 128 cap.
//   Keeps: 1024-thr block per (b,mi), grid 256; fragment-linear fp8 ha;
//   raw lgkm-only barrier; setprio; f direct from L2; exp2 folding
//   (cvt_pk_fp8 saturates); MX fp8 PV (unit scales); bf16 S; proj (512,2).
// Fragment chunk convention (32-row tiles, 16-k chunks, bf16 2B):
//   chunk[tile][q][lane][i] = M[idx = tile*32 + (lane&31)][k = q*16 + (lane>>5)*8 + i]
// 64-wide MX frag convention: lane holds M[lane&31][k = (lane>>5)*32 + i], i=0..31
//   (k indexes the PERMUTED n order; both operands permuted consistently).

#define N_PIX 4096
#define C_IN  512

typedef __attribute__((ext_vector_type(8)))  short bf16x8;
typedef __attribute__((ext_vector_type(16))) float f32x16;
typedef __attribute__((ext_vector_type(8)))  int   i32x8;

__device__ __forceinline__ float fexp2(float x) {
    return __builtin_amdgcn_exp2f(x);   // v_exp_f32 (base-2)
}

__device__ inline unsigned int f2bf(float f) {
    union { float f; unsigned u; } x; x.f = f;
    unsigned r = x.u + 0x7FFFu + ((x.u >> 16) & 1u);
    return r >> 16;
}

__device__ __forceinline__ unsigned cvt_pk_bf16(float a, float b) {
#if __has_builtin(__builtin_amdgcn_cvt_pk_bf16_f32)
    auto r = __builtin_amdgcn_cvt_pk_bf16_f32(a, b);
    unsigned u; __builtin_memcpy(&u, &r, 4); return u;
#else
    return f2bf(a) | (f2bf(b) << 16);
#endif
}

// pack 4 floats -> 4 OCP e4m3 bytes (HW-saturating)
__device__ __forceinline__ unsigned pk_fp8x4(float a, float b, float c, float d) {
    int v = 0;
    v = __builtin_amdgcn_cvt_pk_fp8_f32(a, b, v, false);
    v = __builtin_amdgcn_cvt_pk_fp8_f32(c, d, v, true);
    return (unsigned)v;
}

#define RAW_BARRIER() do { \
    __builtin_amdgcn_sched_barrier(0); \
    asm volatile("s_waitcnt lgkmcnt(0)" ::: "memory"); \
    __builtin_amdgcn_s_barrier(); \
    __builtin_amdgcn_sched_barrier(0); \
} while (0)

// ---------------------------------------------------------------------------
// pack_w (coalesced): grid 20, block 256. Tile tt: 0-1 f_w, 2-3 g_w, 4-19 h_w.
// f_w pre-scaled by 1/ln2 so attn can use exp2 directly.
__global__ __launch_bounds__(256) void pack_w(
    const float* __restrict__ f_w, const float* __restrict__ g_w,
    const float* __restrict__ h_w, unsigned short* __restrict__ wall)
{
    __shared__ __align__(16) unsigned short Ls[32 * 520];
    const int t  = threadIdx.x;
    const int tt = blockIdx.x;
    const float* W; int rbase;
    if (tt < 2)      { W = f_w; rbase = tt * 32; }
    else if (tt < 4) { W = g_w; rbase = (tt - 2) * 32; }
    else             { W = h_w; rbase = (tt - 4) * 32; }
    const float fs = (tt < 2) ? 1.442695041f : 1.0f;

    #pragma unroll
    for (int k = 0; k < 16; ++k) {
        const int off = (t + k * 256) * 4;
        const int row = off >> 9, col = off & 511;
        float4 v = *(const float4*)&W[(size_t)(rbase + row) * C_IN + col];
        uint2 pk; pk.x = cvt_pk_bf16(v.x * fs, v.y * fs); pk.y = cvt_pk_bf16(v.z * fs, v.w * fs);
        *(uint2*)&Ls[row * 520 + col] = pk;
    }
    __syncthreads();
    #pragma unroll
    for (int j = 0; j < 8; ++j) {
        const int o = t + j * 256;
        const int q = o >> 6, lq = o & 63;
        const int row = lq & 31, c0 = q * 16 + (lq >> 5) * 8;
        uint4 pk = *(const uint4*)&Ls[row * 520 + c0];
        *(uint4*)&wall[(size_t)tt * 16384 + (size_t)o * 8] = pk;
    }
}

// ---------------------------------------------------------------------------
// proj_v19: r17 structure, launch_bounds (512,2) -> VGPR cap 128.
__global__ __launch_bounds__(512, 2) void proj_kernel(
    const float* __restrict__ x,
    const unsigned short* __restrict__ wall,
    const float* __restrict__ f_b, const float* __restrict__ g_b,
    const float* __restrict__ h_b,
    unsigned short* __restrict__ fa, unsigned short* __restrict__ gbuf,
    unsigned char* __restrict__ ha)
{
    __shared__ __align__(16) unsigned short Xf[2][4096];   // 16 KB
    const int t    = threadIdx.x;
    const int w    = t >> 6;
    const int l    = t & 63;
    const int half = l >> 5;
    const int tx = t & 15;
    const int ty = t >> 4;
    const int c0 = ty * 2;
    const int qs = c0 >> 4;
    const int woff = (c0 & 7);
    const int hfs = (c0 >> 3) & 1;

    const int blk = blockIdx.x;

    if (blk < 256) {
        // ================= h-path: 16 c-tiles x 64 n =================
        const int b  = blk >> 6;
        const int nb = blk & 63;
        const int n0g = nb * 64;
        const int n0 = tx * 4;

        f32x16 acc[2][2];
        #pragma unroll
        for (int j = 0; j < 2; ++j)
            #pragma unroll
            for (int s = 0; s < 2; ++s)
                #pragma unroll
                for (int r = 0; r < 16; ++r) acc[j][s][r] = 0.f;

        const unsigned short* wp0 = wall + (size_t)(4 + w * 2) * 16384 + (size_t)l * 8;
        const unsigned short* wp1 = wp0 + 16384;
        bf16x8 wc0 = *(const bf16x8*)wp0;
        bf16x8 wc1 = *(const bf16x8*)wp1;

        float4 v0 = *(const float4*)&x[((size_t)(b * C_IN + c0)) * N_PIX + n0g + n0];
        float4 v1 = *(const float4*)&x[((size_t)(b * C_IN + c0 + 1)) * N_PIX + n0g + n0];

        for (int it = 0; it < 8; ++it) {
            {
                unsigned short* xb = &Xf[it & 1][0];
                const float a0[4] = {v0.x, v0.y, v0.z, v0.w};
                const float a1[4] = {v1.x, v1.y, v1.z, v1.w};
                #pragma unroll
                for (int j = 0; j < 4; ++j) {
                    const int n = n0 + j;
                    const int off = ((n >> 5) * 4 + qs) * 512
                                  + ((n & 31) + 32 * hfs) * 8 + woff;
                    *(unsigned*)&xb[off] = cvt_pk_bf16(a0[j], a1[j]);
                }
            }
            if (it < 7) {
                v0 = *(const float4*)&x[((size_t)(b * C_IN + (it + 1) * 64 + c0)) * N_PIX + n0g + n0];
                v1 = *(const float4*)&x[((size_t)(b * C_IN + (it + 1) * 64 + c0 + 1)) * N_PIX + n0g + n0];
            }
            RAW_BARRIER();   // publish ds_writes; x prefetch rides across
            const unsigned short* xb = &Xf[it & 1][0];
            #pragma unroll
            for (int q = 0; q < 4; ++q) {
                const int qn = (it * 4 + q + 1) & 31;
                bf16x8 wn0 = *(const bf16x8*)(wp0 + (size_t)qn * 512);
                bf16x8 wn1 = *(const bf16x8*)(wp1 + (size_t)qn * 512);
                bf16x8 x0 = *(const bf16x8*)&xb[(0 * 4 + q) * 512 + l * 8];
                bf16x8 x1 = *(const bf16x8*)&xb[(1 * 4 + q) * 512 + l * 8];
                acc[0][0] = __builtin_amdgcn_mfma_f32_32x32x16_bf16(x0, wc0, acc[0][0], 0, 0, 0);
                acc[0][1] = __builtin_amdgcn_mfma_f32_32x32x16_bf16(x1, wc0, acc[0][1], 0, 0, 0);
                acc[1][0] = __builtin_amdgcn_mfma_f32_32x32x16_bf16(x0, wc1, acc[1][0], 0, 0, 0);
                acc[1][1] = __builtin_amdgcn_mfma_f32_32x32x16_bf16(x1, wc1, acc[1][1], 0, 0, 0);
                wc0 = wn0; wc1 = wn1;
            }
            // no trailing barrier: read(it) and write(it+2) are separated
            // by barrier(it+1); write(it+1) targets the other buffer.
        }

        // epilogue: fragment-linear fp8 ha. nt = nb>>1, kt = nb&1.
        const int nt_ = nb >> 1, kt_ = nb & 1;
        #pragma unroll
        for (int j = 0; j < 2; ++j) {
            const int ctile = w * 2 + j;
            const int ch = ctile * 32 + (l & 31);
            const float hb = h_b[ch];
            unsigned char* hdst = ha
                + (((size_t)(b * 16 + ctile) * 32 + nt_) * 2 + kt_) * 2048
                + (size_t)(l & 31) * 32 + 16 * half;
            #pragma unroll
            for (int ns = 0; ns < 2; ++ns) {
                uint4 pk4;
                pk4.x = pk_fp8x4(acc[j][ns][0]  + hb, acc[j][ns][1]  + hb,
                                 acc[j][ns][2]  + hb, acc[j][ns][3]  + hb);
                pk4.y = pk_fp8x4(acc[j][ns][4]  + hb, acc[j][ns][5]  + hb,
                                 acc[j][ns][6]  + hb, acc[j][ns][7]  + hb);
                pk4.z = pk_fp8x4(acc[j][ns][8]  + hb, acc[j][ns][9]  + hb,
                                 acc[j][ns][10] + hb, acc[j][ns][11] + hb);
                pk4.w = pk_fp8x4(acc[j][ns][12] + hb, acc[j][ns][13] + hb,
                                 acc[j][ns][14] + hb, acc[j][ns][15] + hb);
                *(uint4*)&hdst[ns * 1024] = pk4;   // (row + 32*ns)*32
            }
        }
    } else {
        // ========== fg-path: 4 tiles x 64 n (256 blocks, 1 ntile/wave) =====
        const int blk2 = blk - 256;
        const int b   = blk2 >> 6;
        const int nb2 = blk2 & 63;
        const int n0g = nb2 * 64;
        const int n0 = tx * 4;
        const int tt    = w & 3;
        const int npair = w >> 2;

        f32x16 acc;
        #pragma unroll
        for (int r = 0; r < 16; ++r) acc[r] = 0.f;

        const unsigned short* wpf = wall + (size_t)tt * 16384 + (size_t)l * 8;
        bf16x8 wcf = *(const bf16x8*)wpf;

        float4 v0 = *(const float4*)&x[((size_t)(b * C_IN + c0)) * N_PIX + n0g + n0];
        float4 v1 = *(const float4*)&x[((size_t)(b * C_IN + c0 + 1)) * N_PIX + n0g + n0];

        for (int it = 0; it < 8; ++it) {
            {
                unsigned short* xb = &Xf[it & 1][0];
                const float a0[4] = {v0.x, v0.y, v0.z, v0.w};
                const float a1[4] = {v1.x, v1.y, v1.z, v1.w};
                #pragma unroll
                for (int j = 0; j < 4; ++j) {
                    const int n = n0 + j;
                    const int off = ((n >> 5) * 4 + qs) * 512
                                  + ((n & 31) + 32 * hfs) * 8 + woff;
                    *(unsigned*)&xb[off] = cvt_pk_bf16(a0[j], a1[j]);
                }
            }
            if (it < 7) {
                v0 = *(const float4*)&x[((size_t)(b * C_IN + (it + 1) * 64 + c0)) * N_PIX + n0g + n0];
                v1 = *(const float4*)&x[((size_t)(b * C_IN + (it + 1) * 64 + c0 + 1)) * N_PIX + n0g + n0];
            }
            RAW_BARRIER();
            const unsigned short* xb = &Xf[it & 1][0];
            #pragma unroll
            for (int q = 0; q < 4; ++q) {
                const int qn = (it * 4 + q + 1) & 31;
                bf16x8 wnf = *(const bf16x8*)(wpf + (size_t)qn * 512);
                bf16x8 x0 = *(const bf16x8*)&xb[(npair * 4 + q) * 512 + l * 8];
                acc = __builtin_amdgcn_mfma_f32_32x32x16_bf16(wcf, x0, acc, 0, 0, 0);
                wcf = wnf;
            }
        }

        unsigned short* buf = (tt < 2) ? fa : gbuf;
        const float* bias = (tt < 2) ? f_b : g_b;
        const float bscale = (tt < 2) ? 1.442695041f : 1.0f;
        const int ntile = nb2 * 2 + npair;
        #pragma unroll
        for (int j2 = 0; j2 < 4; ++j2) {
            const int o_base = (tt & 1) * 32 + 8 * j2 + 4 * half;
            float4 bv = *(const float4*)&bias[o_base];
            bv.x *= bscale; bv.y *= bscale; bv.z *= bscale; bv.w *= bscale;
            const int q  = o_base >> 4;
            const int lp = (l & 31) + 32 * (j2 & 1);
            uint2 pk;
            pk.x = cvt_pk_bf16(acc[4 * j2 + 0] + bv.x, acc[4 * j2 + 1] + bv.y);
            pk.y = cvt_pk_bf16(acc[4 * j2 + 2] + bv.z, acc[4 * j2 + 3] + bv.w);
            size_t off = (((size_t)(b * 128 + ntile) * 4 + q) * 64 + lp) * 8 + 4 * half;
            *(uint2*)&buf[off] = pk;
        }
    }
}

// ---------------------------------------------------------------------------
// attn_v20: balanced roles. Producers (w0-7): S + exp + E-write ONLY.
// Consumers (w8-15): PV of 2 ctg each (E frags shared between ctg).
// grid 256 (= (b,mi)), 1024 threads, 1 block/CU, VGPR cap 128.
__global__ __launch_bounds__(1024, 1) void attn_kernel(
    const unsigned short* __restrict__ fa,
    const unsigned short* __restrict__ gbuf,
    const unsigned char* __restrict__ ha,
    const float* __restrict__ x,
    const float* __restrict__ gamma_p,
    float* __restrict__ out)
{
    __shared__ __align__(16) unsigned char Ebuf[2][64 * 136];  // 17.4 KB (fp8 E)
    __shared__ float den_part[4][64];
    __shared__ float den_inv[64];

    const int t    = threadIdx.x;
    const int w    = t >> 6;          // 0..15
    const int l    = t & 63;
    const int lane = l & 31;
    const int half = l >> 5;
    const bool prod = (w < 8);        // producer waves (wave-uniform)
    const int nsub = w & 3;           // producer S/E role (valid for w<8)
    const int mt   = w >> 2;          // (valid for w<8)

    const int blk = blockIdx.x;
    const int b   = blk & 3;
    const int mi  = blk >> 2;         // 0..63
    const int m0  = mi * 64;

    float denp = 0.f;

    if (prod) {
        // =============== PRODUCER: S + exp + E-write ===============
        bf16x8 gfrag[4];
        bf16x8 ff[4];
        const unsigned short* fptr = fa + (size_t)b * (128 * 4) * 512
                                   + (size_t)(nsub * 4) * 512 + (size_t)l * 8;
        {
            const unsigned short* gp = gbuf
                + ((size_t)(b * 128 + mi * 2 + mt) * 4) * 512 + (size_t)l * 8;
            #pragma unroll
            for (int q = 0; q < 4; ++q)
                gfrag[q] = *(const bf16x8*)(gp + (size_t)q * 512);
        }
        #pragma unroll
        for (int q = 0; q < 4; ++q)
            ff[q] = *(const bf16x8*)(fptr + (size_t)q * 512);
        fptr += 8192;

        // prologue: S(0), exp(0), write slot0
        {
            f32x16 s;
            #pragma unroll
            for (int r = 0; r < 16; ++r) s[r] = 0.f;
            #pragma unroll
            for (int q = 0; q < 4; ++q)
                s = __builtin_amdgcn_mfma_f32_32x32x16_bf16(ff[q], gfrag[q], s, 0, 0, 0);
            #pragma unroll
            for (int q = 0; q < 4; ++q)
                ff[q] = *(const bf16x8*)(fptr + (size_t)q * 512);
            fptr += 8192;
            unsigned pkv[4];
            #pragma unroll
            for (int r4 = 0; r4 < 4; ++r4) {
                float e0 = fexp2(s[r4 * 4 + 0] - 8.656170f);
                float e1 = fexp2(s[r4 * 4 + 1] - 8.656170f);
                float e2 = fexp2(s[r4 * 4 + 2] - 8.656170f);
                float e3 = fexp2(s[r4 * 4 + 3] - 8.656170f);
                denp += (e0 + e1) + (e2 + e3);
                pkv[r4] = pk_fp8x4(e0, e1, e2, e3);
            }
            unsigned char* ew = &Ebuf[0][(mt * 32 + lane) * 136 + nsub * 32 + half * 16];
            *(unsigned long long*)(ew)     = (unsigned long long)pkv[0]
                                           | ((unsigned long long)pkv[1] << 32);
            *(unsigned long long*)(ew + 8) = (unsigned long long)pkv[2]
                                           | ((unsigned long long)pkv[3] << 32);
        }
        RAW_BARRIER();

        for (int nt = 0; nt < 31; ++nt) {
            // S(nt+1)
            __builtin_amdgcn_s_setprio(1);
            f32x16 s;
            #pragma unroll
            for (int r = 0; r < 16; ++r) s[r] = 0.f;
            #pragma unroll
            for (int q = 0; q < 4; ++q)
                s = __builtin_amdgcn_mfma_f32_32x32x16_bf16(ff[q], gfrag[q], s, 0, 0, 0);
            #pragma unroll
            for (int q = 0; q < 4; ++q)
                ff[q] = *(const bf16x8*)(fptr + (size_t)q * 512);
            fptr += 8192;
            __builtin_amdgcn_s_setprio(0);
            // exp(nt+1) + E-write slot (nt+1)&1
            unsigned pkv[4];
            #pragma unroll
            for (int r4 = 0; r4 < 4; ++r4) {
                float e0 = fexp2(s[r4 * 4 + 0] - 8.656170f);
                float e1 = fexp2(s[r4 * 4 + 1] - 8.656170f);
                float e2 = fexp2(s[r4 * 4 + 2] - 8.656170f);
                float e3 = fexp2(s[r4 * 4 + 3] - 8.656170f);
                denp += (e0 + e1) + (e2 + e3);
                pkv[r4] = pk_fp8x4(e0, e1, e2, e3);
            }
            unsigned char* ew = &Ebuf[(nt + 1) & 1][(mt * 32 + lane) * 136 + nsub * 32 + half * 16];
            *(unsigned long long*)(ew)     = (unsigned long long)pkv[0]
                                           | ((unsigned long long)pkv[1] << 32);
            *(unsigned long long*)(ew + 8) = (unsigned long long)pkv[2]
                                           | ((unsigned long long)pkv[3] << 32);
            RAW_BARRIER();
        }

        // denominator partials
        denp += __shfl_xor(denp, 32, 64);
        if (l < 32) den_part[nsub][mt * 32 + lane] = denp;
        __syncthreads();
        if (t < 64) {
            float d = den_part[0][t] + den_part[1][t] + den_part[2][t] + den_part[3][t];
            den_inv[t] = 1.0f / d;
        }
        __syncthreads();
        // producers write no output
    } else {
        // =============== CONSUMER: PV of 2 ctg ===============
        const int cw  = w - 8;            // 0..7
        const int cA  = cw * 2;           // ctg A
        const int cB  = cA + 1;           // ctg B
        f32x16 accA[2], accB[2];
        #pragma unroll
        for (int j = 0; j < 2; ++j)
            #pragma unroll
            for (int r = 0; r < 16; ++r) { accA[j][r] = 0.f; accB[j][r] = 0.f; }

        const unsigned char* hpA = ha + (size_t)(b * 16 + cA) * 131072 + (size_t)l * 32;
        const unsigned char* hpB = ha + (size_t)(b * 16 + cB) * 131072 + (size_t)l * 32;
        i32x8 hA0 = *(const i32x8*)hpA;
        i32x8 hA1 = *(const i32x8*)(hpA + 2048);
        i32x8 hB0 = *(const i32x8*)hpB;
        i32x8 hB1 = *(const i32x8*)(hpB + 2048);
        hpA += 4096; hpB += 4096;

        RAW_BARRIER();   // matches producer prologue barrier

        for (int nt = 0; nt < 31; ++nt) {
            __builtin_amdgcn_s_setprio(1);
            const unsigned char* eb = &Ebuf[nt & 1][0];
            #pragma unroll
            for (int kt = 0; kt < 2; ++kt) {
                const unsigned char* e0p = eb + lane * 136 + kt * 64 + half * 32;
                union { i32x8 v; long d[4]; } b0, b1;
                #pragma unroll
                for (int j = 0; j < 4; ++j) {
                    b0.d[j] = *(const long*)(e0p + 8 * j);
                    b1.d[j] = *(const long*)(e0p + 32 * 136 + 8 * j);
                }
                const i32x8 avA = kt ? hA1 : hA0;
                const i32x8 avB = kt ? hB1 : hB0;
                accA[0] = __builtin_amdgcn_mfma_scale_f32_32x32x64_f8f6f4(
                    avA, b0.v, accA[0], 0, 0, 0, 127, 0, 127);
                accA[1] = __builtin_amdgcn_mfma_scale_f32_32x32x64_f8f6f4(
                    avA, b1.v, accA[1], 0, 0, 0, 127, 0, 127);
                accB[0] = __builtin_amdgcn_mfma_scale_f32_32x32x64_f8f6f4(
                    avB, b0.v, accB[0], 0, 0, 0, 127, 0, 127);
                accB[1] = __builtin_amdgcn_mfma_scale_f32_32x32x64_f8f6f4(
                    avB, b1.v, accB[1], 0, 0, 0, 127, 0, 127);
            }
            __builtin_amdgcn_s_setprio(0);
            // prefetch h(nt+1) for both ctg
            hA0 = *(const i32x8*)hpA;
            hA1 = *(const i32x8*)(hpA + 2048);
            hB0 = *(const i32x8*)hpB;
            hB1 = *(const i32x8*)(hpB + 2048);
            hpA += 4096; hpB += 4096;
            RAW_BARRIER();
        }

        // epilogue: PV(31)
        {
            const unsigned char* eb = &Ebuf[31 & 1][0];
            #pragma unroll
            for (int kt = 0; kt < 2; ++kt) {
                const unsigned char* e0p = eb + lane * 136 + kt * 64 + half * 32;
                union { i32x8 v; long d[4]; } b0, b1;
                #pragma unroll
                for (int j = 0; j < 4; ++j) {
                    b0.d[j] = *(const long*)(e0p + 8 * j);
                    b1.d[j] = *(const long*)(e0p + 32 * 136 + 8 * j);
                }
                const i32x8 avA = kt ? hA1 : hA0;
                const i32x8 avB = kt ? hB1 : hB0;
                accA[0] = __builtin_amdgcn_mfma_scale_f32_32x32x64_f8f6f4(
                    avA, b0.v, accA[0], 0, 0, 0, 127, 0, 127);
                accA[1] = __builtin_amdgcn_mfma_scale_f32_32x32x64_f8f6f4(
                    avA, b1.v, accA[1], 0, 0, 0, 127, 0, 127);
                accB[0] = __builtin_amdgcn_mfma_scale_f32_32x32x64_f8f6f4(
                    avB, b0.v, accB[0], 0, 0, 0, 127, 0, 127);
                accB[1] = __builtin_amdgcn_mfma_scale_f32_32x32x64_f8f6f4(
                    avB, b1.v, accB[1], 0, 0, 0, 127, 0, 127);
            }
        }

        __syncthreads();   // matches producer den_part sync
        __syncthreads();   // matches producer den_inv sync

        // output: 2 ctg per consumer wave
        const float gs = gamma_p[0];
        #pragma unroll
        for (int mt2 = 0; mt2 < 2; ++mt2) {
            const int mloc = mt2 * 32 + lane;
            const float dinv = den_inv[mloc];
            const int m = m0 + mloc;
            #pragma unroll
            for (int r = 0; r < 16; ++r) {
                const int co = (r & 3) + ((r >> 2) * 8) + half * 4;
                const size_t idxA = ((size_t)(b * C_IN + cA * 32 + co)) * N_PIX + m;
                const size_t idxB = ((size_t)(b * C_IN + cB * 32 + co)) * N_PIX + m;
                out[idxA] = gs * accA[mt2][r] * dinv + x[idxA];
                out[idxB] = gs * accB[mt2][r] * dinv + x[idxB];
            }
        }
    }
}

// ---------------------------------------------------------------------------
extern "C" void kernel_launch(void* const* d_in, const int* in_sizes, int n_in,
                              void* d_out, int out_size, void* d_ws, size_t ws_size,
                              hipStream_t stream)
{
    const float* x     = (const float*)d_in[0];
    const float* f_w   = (const float*)d_in[1];
    const float* f_b   = (const float*)d_in[2];
    const float* g_w   = (const float*)d_in[3];
    const float* g_b   = (const float*)d_in[4];
    const float* h_w   = (const float*)d_in[5];
    const float* h_b   = (const float*)d_in[6];
    const float* gamma = (const float*)d_in[7];
    float* out = (float*)d_out;

    unsigned short* fa   = (unsigned short*)d_ws;        // 1M shorts (2 MB)
    unsigned short* gbuf = fa + (1u << 20);              // 1M shorts (2 MB)
    unsigned char*  ha   = (unsigned char*)(gbuf + (1u << 20));  // 8 MB fp8 fragment-linear
    unsigned short* wall = (unsigned short*)(ha + (8u << 20));   // 640 KB

    pack_w<<<20, 256, 0, stream>>>(f_w, g_w, h_w, wall);

    proj_kernel<<<512, 512, 0, stream>>>(x, wall, f_b, g_b, h_b, fa, gbuf, ha);

    attn_kernel<<<256, 1024, 0, stream>>>(fa, gbuf, ha, x, gamma, out);
}